// Round 1
// baseline (192.075 us; speedup 1.0000x reference)
//
#include <hip/hip_runtime.h>
#include <math.h>

#define NRAYS   1048576
#define NSPH    4
#define TEXH    2048
#define TEXW    2048
#define NCH     4
#define DIN     16      // NSPH * NCH
#define HID     32
#define NOUT    3
#define LN_EPS  1e-5f

__device__ __forceinline__ float4 lerp4(const float4 a, const float4 b, const float t) {
    float4 r;
    r.x = a.x + t * (b.x - a.x);
    r.y = a.y + t * (b.y - a.y);
    r.z = a.z + t * (b.z - a.z);
    r.w = a.w + t * (b.w - a.w);
    return r;
}

__global__ __launch_bounds__(256) void ray_mlp_kernel(
    const float* __restrict__ inputs,     // (B, 8)
    const float* __restrict__ tex,        // (4, 2048, 2048, 4)
    const float* __restrict__ w_in,       // (16, 32)
    const float* __restrict__ b_in,       // (32,)
    const float* __restrict__ g_in,       // (32,)
    const float* __restrict__ bt_in,      // (32,)
    const float* __restrict__ w_hid,      // (2, 32, 32)
    const float* __restrict__ b_hid,      // (2, 32)
    const float* __restrict__ g_hid,      // (2, 32)
    const float* __restrict__ bt_hid,     // (2, 32)
    const float* __restrict__ w_out,      // (32, 3)
    const float* __restrict__ b_out,      // (3,)
    float* __restrict__ out)              // (B, 3)
{
    const int ray = blockIdx.x * 256 + threadIdx.x;

    // ---- load the 8 per-ray angles (two coalesced float4 loads) ----
    const float4 in0 = *reinterpret_cast<const float4*>(inputs + (size_t)ray * 8);
    const float4 in1 = *reinterpret_cast<const float4*>(inputs + (size_t)ray * 8 + 4);

    // ---- bilinear gather from each sphere texture ----
    float x[DIN];
    const float inv2pi = 0.15915494309189535f;  // 1/(2*pi)
    const float invpi  = 0.3183098861837907f;   // 1/pi

    #pragma unroll
    for (int s = 0; s < NSPH; ++s) {
        const float th = (s == 0) ? in0.x : (s == 1) ? in0.z : (s == 2) ? in1.x : in1.z;
        const float ph = (s == 0) ? in0.y : (s == 1) ? in0.w : (s == 2) ? in1.y : in1.w;
        float t = th * inv2pi;
        float p = ph * invpi;
        const bool fin = isfinite(t) && isfinite(p);
        // nan_to_num: non-finite coords sample at 0; result is zeroed below anyway
        t = fin ? t : 0.0f;
        p = fin ? p : 0.0f;

        const float fx = t * (float)(TEXW - 1);
        const float fy = p * (float)(TEXH - 1);
        const float fx0 = floorf(fx), fx1 = ceilf(fx);
        const float fy0 = floorf(fy), fy1 = ceilf(fy);
        const float xf = fx - fx0;
        const float yf = fy - fy0;
        // JAX gathers clamp OOB indices; clamp to match
        const int x0 = min(max((int)fx0, 0), TEXW - 1);
        const int x1 = min(max((int)fx1, 0), TEXW - 1);
        const int y0 = min(max((int)fy0, 0), TEXH - 1);
        const int y1 = min(max((int)fy1, 0), TEXH - 1);

        const float4* img = reinterpret_cast<const float4*>(tex) + (size_t)s * TEXH * TEXW;
        const float4 t00 = img[(size_t)y0 * TEXW + x0];
        const float4 t01 = img[(size_t)y0 * TEXW + x1];
        const float4 t10 = img[(size_t)y1 * TEXW + x0];
        const float4 t11 = img[(size_t)y1 * TEXW + x1];

        const float4 top = lerp4(t00, t01, xf);
        const float4 bot = lerp4(t10, t11, xf);
        const float4 res = lerp4(top, bot, yf);

        x[4 * s + 0] = fin ? res.x : 0.0f;
        x[4 * s + 1] = fin ? res.y : 0.0f;
        x[4 * s + 2] = fin ? res.z : 0.0f;
        x[4 * s + 3] = fin ? res.w : 0.0f;
    }

    // ---- layer in: (16) @ (16,32) + LN + relu ----
    float h[HID];
    {
        float pre[HID];
        #pragma unroll
        for (int j = 0; j < HID; ++j) {
            float acc = b_in[j];
            #pragma unroll
            for (int k = 0; k < DIN; ++k)
                acc = fmaf(x[k], w_in[k * HID + j], acc);
            pre[j] = acc;
        }
        float m = 0.0f;
        #pragma unroll
        for (int j = 0; j < HID; ++j) m += pre[j];
        m *= (1.0f / HID);
        float v = 0.0f;
        #pragma unroll
        for (int j = 0; j < HID; ++j) { const float d = pre[j] - m; v = fmaf(d, d, v); }
        v *= (1.0f / HID);
        const float r = rsqrtf(v + LN_EPS);
        #pragma unroll
        for (int j = 0; j < HID; ++j)
            h[j] = fmaxf(0.0f, fmaf((pre[j] - m) * r, g_in[j], bt_in[j]));
    }

    // ---- 2 hidden layers: (32) @ (32,32) + LN + relu ----
    #pragma unroll 1
    for (int l = 0; l < 2; ++l) {
        const float* __restrict__ wl  = w_hid  + l * HID * HID;
        const float* __restrict__ bl  = b_hid  + l * HID;
        const float* __restrict__ gl  = g_hid  + l * HID;
        const float* __restrict__ btl = bt_hid + l * HID;
        float pre[HID];
        #pragma unroll
        for (int j = 0; j < HID; ++j) {
            float acc = bl[j];
            #pragma unroll
            for (int k = 0; k < HID; ++k)
                acc = fmaf(h[k], wl[k * HID + j], acc);
            pre[j] = acc;
        }
        float m = 0.0f;
        #pragma unroll
        for (int j = 0; j < HID; ++j) m += pre[j];
        m *= (1.0f / HID);
        float v = 0.0f;
        #pragma unroll
        for (int j = 0; j < HID; ++j) { const float d = pre[j] - m; v = fmaf(d, d, v); }
        v *= (1.0f / HID);
        const float r = rsqrtf(v + LN_EPS);
        #pragma unroll
        for (int j = 0; j < HID; ++j)
            h[j] = fmaxf(0.0f, fmaf((pre[j] - m) * r, gl[j], btl[j]));
    }

    // ---- output layer: (32) @ (32,3) ----
    #pragma unroll
    for (int j = 0; j < NOUT; ++j) {
        float acc = b_out[j];
        #pragma unroll
        for (int k = 0; k < HID; ++k)
            acc = fmaf(h[k], w_out[k * NOUT + j], acc);
        out[(size_t)ray * NOUT + j] = acc;
    }
}

extern "C" void kernel_launch(void* const* d_in, const int* in_sizes, int n_in,
                              void* d_out, int out_size, void* d_ws, size_t ws_size,
                              hipStream_t stream) {
    const float* inputs = (const float*)d_in[0];
    const float* tex    = (const float*)d_in[1];
    const float* w_in   = (const float*)d_in[2];
    const float* b_in   = (const float*)d_in[3];
    const float* g_in   = (const float*)d_in[4];
    const float* bt_in  = (const float*)d_in[5];
    const float* w_hid  = (const float*)d_in[6];
    const float* b_hid  = (const float*)d_in[7];
    const float* g_hid  = (const float*)d_in[8];
    const float* bt_hid = (const float*)d_in[9];
    const float* w_out  = (const float*)d_in[10];
    const float* b_out  = (const float*)d_in[11];
    float* out = (float*)d_out;

    ray_mlp_kernel<<<NRAYS / 256, 256, 0, stream>>>(
        inputs, tex, w_in, b_in, g_in, bt_in,
        w_hid, b_hid, g_hid, bt_hid, w_out, b_out, out);
}

// Round 2
// 191.514 us; speedup vs baseline: 1.0029x; 1.0029x over previous
//
#include <hip/hip_runtime.h>
#include <math.h>

#define NRAYS   1048576
#define NSPH    4
#define TEXH    2048
#define TEXW    2048
#define DIN     16      // NSPH * 4 channels
#define HID     32
#define NOUT    3
#define LN_EPS  1e-5f

__device__ __forceinline__ float4 lerp4(const float4 a, const float4 b, const float t) {
    float4 r;
    r.x = fmaf(t, b.x - a.x, a.x);
    r.y = fmaf(t, b.y - a.y, a.y);
    r.z = fmaf(t, b.z - a.z, a.z);
    r.w = fmaf(t, b.w - a.w, a.w);
    return r;
}

// layernorm(pre) * g + bt, relu, into h. g/bt are uniform (scalar loads).
__device__ __forceinline__ void ln_relu(const float* __restrict__ pre,
                                        const float* __restrict__ g,
                                        const float* __restrict__ bt,
                                        float* __restrict__ h) {
    float m = 0.0f;
    #pragma unroll
    for (int j = 0; j < HID; ++j) m += pre[j];
    m *= (1.0f / HID);
    float v = 0.0f;
    #pragma unroll
    for (int j = 0; j < HID; ++j) { const float d = pre[j] - m; v = fmaf(d, d, v); }
    const float r = rsqrtf(fmaf(v, (1.0f / HID), LN_EPS));
    #pragma unroll
    for (int j = 0; j < HID; ++j)
        h[j] = fmaxf(0.0f, fmaf((pre[j] - m) * r, g[j], bt[j]));
}

// pre = h @ W(32,32) + b, k-outer j-inner for contiguous scalar weight rows
__device__ __forceinline__ void mm32(const float* __restrict__ h,
                                     const float* __restrict__ W,
                                     const float* __restrict__ b,
                                     float* __restrict__ pre) {
    #pragma unroll
    for (int j = 0; j < HID; ++j) pre[j] = b[j];
    #pragma unroll
    for (int k = 0; k < HID; ++k) {
        const float hv = h[k];
        #pragma unroll
        for (int j = 0; j < HID; ++j)
            pre[j] = fmaf(hv, W[k * HID + j], pre[j]);
    }
}

__global__ __launch_bounds__(256) void ray_mlp_kernel(
    const float* __restrict__ inputs,     // (B, 8)
    const float* __restrict__ tex,        // (4, 2048, 2048, 4)
    const float* __restrict__ w_in,       // (16, 32)
    const float* __restrict__ b_in,       // (32,)
    const float* __restrict__ g_in,       // (32,)
    const float* __restrict__ bt_in,      // (32,)
    const float* __restrict__ w_hid,      // (2, 32, 32)
    const float* __restrict__ b_hid,      // (2, 32)
    const float* __restrict__ g_hid,      // (2, 32)
    const float* __restrict__ bt_hid,     // (2, 32)
    const float* __restrict__ w_out,      // (32, 3)
    const float* __restrict__ b_out,      // (3,)
    float* __restrict__ out)              // (B, 3)
{
    const int ray = blockIdx.x * 256 + threadIdx.x;

    const float4 in0 = *reinterpret_cast<const float4*>(inputs + (size_t)ray * 8);
    const float4 in1 = *reinterpret_cast<const float4*>(inputs + (size_t)ray * 8 + 4);

    const float inv2pi = 0.15915494309189535f;
    const float invpi  = 0.3183098861837907f;

    const float th[NSPH] = {in0.x, in0.z, in1.x, in1.z};
    const float ph[NSPH] = {in0.y, in0.w, in1.y, in1.w};

    // ---- phase 1: all 16 gather addresses ----
    float xf[NSPH], yf[NSPH];
    float fmask[NSPH];
    const float4* p00[NSPH];
    const float4* p01[NSPH];
    const float4* p10[NSPH];
    const float4* p11[NSPH];
    #pragma unroll
    for (int s = 0; s < NSPH; ++s) {
        float t = th[s] * inv2pi;
        float p = ph[s] * invpi;
        const bool fin = isfinite(t) && isfinite(p);
        fmask[s] = fin ? 1.0f : 0.0f;
        t = fin ? t : 0.0f;
        p = fin ? p : 0.0f;
        const float fx = t * (float)(TEXW - 1);
        const float fy = p * (float)(TEXH - 1);
        const float fx0 = floorf(fx), fy0 = floorf(fy);
        xf[s] = fx - fx0;
        yf[s] = fy - fy0;
        const int x0 = min(max((int)fx0, 0), TEXW - 1);
        const int x1 = min(max((int)ceilf(fx), 0), TEXW - 1);
        const int y0 = min(max((int)fy0, 0), TEXH - 1);
        const int y1 = min(max((int)ceilf(fy), 0), TEXH - 1);
        const float4* img = reinterpret_cast<const float4*>(tex) + (size_t)s * TEXH * TEXW;
        p00[s] = img + (size_t)y0 * TEXW + x0;
        p01[s] = img + (size_t)y0 * TEXW + x1;
        p10[s] = img + (size_t)y1 * TEXW + x0;
        p11[s] = img + (size_t)y1 * TEXW + x1;
    }

    // ---- phase 2: issue ALL 16 texel loads (single progressive vmcnt chain) ----
    float4 t00[NSPH], t01[NSPH], t10[NSPH], t11[NSPH];
    #pragma unroll
    for (int s = 0; s < NSPH; ++s) {
        t00[s] = *p00[s];
        t01[s] = *p01[s];
        t10[s] = *p10[s];
        t11[s] = *p11[s];
    }

    // ---- phase 3: bilinear lerps -> x[16] ----
    float x[DIN];
    #pragma unroll
    for (int s = 0; s < NSPH; ++s) {
        const float4 top = lerp4(t00[s], t01[s], xf[s]);
        const float4 bot = lerp4(t10[s], t11[s], xf[s]);
        const float4 res = lerp4(top, bot, yf[s]);
        x[4 * s + 0] = res.x * fmask[s];
        x[4 * s + 1] = res.y * fmask[s];
        x[4 * s + 2] = res.z * fmask[s];
        x[4 * s + 3] = res.w * fmask[s];
    }

    // ---- layer in: (16) @ (16,32) + LN + relu ----
    float pre[HID], h[HID];
    #pragma unroll
    for (int j = 0; j < HID; ++j) pre[j] = b_in[j];
    #pragma unroll
    for (int k = 0; k < DIN; ++k) {
        const float xv = x[k];
        #pragma unroll
        for (int j = 0; j < HID; ++j)
            pre[j] = fmaf(xv, w_in[k * HID + j], pre[j]);
    }
    ln_relu(pre, g_in, bt_in, h);

    // ---- hidden layer 0 ----
    mm32(h, w_hid, b_hid, pre);
    ln_relu(pre, g_hid, bt_hid, h);

    // ---- hidden layer 1 ----
    mm32(h, w_hid + HID * HID, b_hid + HID, pre);
    ln_relu(pre, g_hid + HID, bt_hid + HID, h);

    // ---- output layer: (32) @ (32,3) ----
    float o0 = b_out[0], o1 = b_out[1], o2 = b_out[2];
    #pragma unroll
    for (int k = 0; k < HID; ++k) {
        const float hv = h[k];
        o0 = fmaf(hv, w_out[k * NOUT + 0], o0);
        o1 = fmaf(hv, w_out[k * NOUT + 1], o1);
        o2 = fmaf(hv, w_out[k * NOUT + 2], o2);
    }
    out[(size_t)ray * NOUT + 0] = o0;
    out[(size_t)ray * NOUT + 1] = o1;
    out[(size_t)ray * NOUT + 2] = o2;
}

extern "C" void kernel_launch(void* const* d_in, const int* in_sizes, int n_in,
                              void* d_out, int out_size, void* d_ws, size_t ws_size,
                              hipStream_t stream) {
    const float* inputs = (const float*)d_in[0];
    const float* tex    = (const float*)d_in[1];
    const float* w_in   = (const float*)d_in[2];
    const float* b_in   = (const float*)d_in[3];
    const float* g_in   = (const float*)d_in[4];
    const float* bt_in  = (const float*)d_in[5];
    const float* w_hid  = (const float*)d_in[6];
    const float* b_hid  = (const float*)d_in[7];
    const float* g_hid  = (const float*)d_in[8];
    const float* bt_hid = (const float*)d_in[9];
    const float* w_out  = (const float*)d_in[10];
    const float* b_out  = (const float*)d_in[11];
    float* out = (float*)d_out;

    ray_mlp_kernel<<<NRAYS / 256, 256, 0, stream>>>(
        inputs, tex, w_in, b_in, g_in, bt_in,
        w_hid, b_hid, g_hid, bt_hid, w_out, b_out, out);
}

// Round 3
// 189.796 us; speedup vs baseline: 1.0120x; 1.0091x over previous
//
#include <hip/hip_runtime.h>
#include <math.h>
#include <stdint.h>

#define NRAYS   1048576
#define NSPH    4
#define TEXH    2048
#define TEXW    2048
#define DIN     16      // NSPH * 4 channels
#define HID     32
#define NOUT    3
#define LN_EPS  1e-5f

__device__ __forceinline__ float4 lerp4(const float4 a, const float4 b, const float t) {
    float4 r;
    r.x = fmaf(t, b.x - a.x, a.x);
    r.y = fmaf(t, b.y - a.y, a.y);
    r.z = fmaf(t, b.z - a.z, a.z);
    r.w = fmaf(t, b.w - a.w, a.w);
    return r;
}

// layernorm(pre) * g + bt, relu, into h
__device__ __forceinline__ void ln_relu(const float* __restrict__ pre,
                                        const float* __restrict__ g,
                                        const float* __restrict__ bt,
                                        float* __restrict__ h) {
    float m = 0.0f;
    #pragma unroll
    for (int j = 0; j < HID; ++j) m += pre[j];
    m *= (1.0f / HID);
    float v = 0.0f;
    #pragma unroll
    for (int j = 0; j < HID; ++j) { const float d = pre[j] - m; v = fmaf(d, d, v); }
    const float r = rsqrtf(fmaf(v, (1.0f / HID), LN_EPS));
    #pragma unroll
    for (int j = 0; j < HID; ++j)
        h[j] = fmaxf(0.0f, fmaf((pre[j] - m) * r, g[j], bt[j]));
}

// pre = h @ W(32,32) + b, k-outer j-inner (contiguous uniform weight rows -> s_load bursts)
__device__ __forceinline__ void mm32(const float* __restrict__ h,
                                     const float* __restrict__ W,
                                     const float* __restrict__ b,
                                     float* __restrict__ pre) {
    #pragma unroll
    for (int j = 0; j < HID; ++j) pre[j] = b[j];
    #pragma unroll
    for (int k = 0; k < HID; ++k) {
        const float hv = h[k];
        #pragma unroll
        for (int j = 0; j < HID; ++j)
            pre[j] = fmaf(hv, W[k * HID + j], pre[j]);
    }
}

// __launch_bounds__(256, 4): 4 waves/SIMD min -> VGPR budget 128. Without this the
// allocator targets 8 waves/SIMD (64 VGPR) and rematerializes the layernorm per
// j-chunk (observed: VGPR_Count=44, ~2x VALU issue, 43% VALUBusy).
__global__ __launch_bounds__(256, 4) void ray_mlp_kernel(
    const float* __restrict__ inputs,     // (B, 8)
    const float* __restrict__ tex,        // (4, 2048, 2048, 4)
    const float* __restrict__ w_in,       // (16, 32)
    const float* __restrict__ b_in,       // (32,)
    const float* __restrict__ g_in,       // (32,)
    const float* __restrict__ bt_in,      // (32,)
    const float* __restrict__ w_hid,      // (2, 32, 32)
    const float* __restrict__ b_hid,      // (2, 32)
    const float* __restrict__ g_hid,      // (2, 32)
    const float* __restrict__ bt_hid,     // (2, 32)
    const float* __restrict__ w_out,      // (32, 3)
    const float* __restrict__ b_out,      // (3,)
    float* __restrict__ out)              // (B, 3)
{
    const int ray = blockIdx.x * 256 + threadIdx.x;

    const float4 in0 = *reinterpret_cast<const float4*>(inputs + (size_t)ray * 8);
    const float4 in1 = *reinterpret_cast<const float4*>(inputs + (size_t)ray * 8 + 4);

    // fused scale: theta/(2pi)*2047, phi/pi*2047
    const float cx = 325.7901685f;   // 2047/(2*pi)
    const float cy = 651.5803370f;   // 2047/pi

    const float th[NSPH] = {in0.x, in0.z, in1.x, in1.z};
    const float ph[NSPH] = {in0.y, in0.w, in1.y, in1.w};

    // ---- phase 1: 16 gather byte-offsets (32-bit; texture is 256 MB) ----
    float xf[NSPH], yf[NSPH], fmask[NSPH];
    uint32_t o00[NSPH], o01[NSPH], o10[NSPH], o11[NSPH];
    #pragma unroll
    for (int s = 0; s < NSPH; ++s) {
        float fx = th[s] * cx;
        float fy = ph[s] * cy;
        const bool fin = isfinite(fx) && isfinite(fy);
        fmask[s] = fin ? 1.0f : 0.0f;
        fx = fin ? fx : 0.0f;
        fy = fin ? fy : 0.0f;
        const float fx0 = floorf(fx), fy0 = floorf(fy);
        xf[s] = fx - fx0;
        yf[s] = fy - fy0;
        const uint32_t x0 = (uint32_t)min(max((int)fx0, 0), TEXW - 1);
        const uint32_t x1 = (uint32_t)min(max((int)ceilf(fx), 0), TEXW - 1);
        const uint32_t y0 = (uint32_t)min(max((int)fy0, 0), TEXH - 1);
        const uint32_t y1 = (uint32_t)min(max((int)ceilf(fy), 0), TEXH - 1);
        const uint32_t sb = (uint32_t)s << 22;         // s * 2048 * 2048
        const uint32_t r0 = sb + (y0 << 11);
        const uint32_t r1 = sb + (y1 << 11);
        o00[s] = (r0 + x0) << 4;                       // * sizeof(float4)
        o01[s] = (r0 + x1) << 4;
        o10[s] = (r1 + x0) << 4;
        o11[s] = (r1 + x1) << 4;
    }

    // ---- phase 2: issue ALL 16 texel loads ----
    const char* texb = reinterpret_cast<const char*>(tex);
    float4 t00[NSPH], t01[NSPH], t10[NSPH], t11[NSPH];
    #pragma unroll
    for (int s = 0; s < NSPH; ++s) {
        t00[s] = *reinterpret_cast<const float4*>(texb + o00[s]);
        t01[s] = *reinterpret_cast<const float4*>(texb + o01[s]);
        t10[s] = *reinterpret_cast<const float4*>(texb + o10[s]);
        t11[s] = *reinterpret_cast<const float4*>(texb + o11[s]);
    }

    // ---- phase 3: bilinear lerps -> x[16] ----
    float x[DIN];
    #pragma unroll
    for (int s = 0; s < NSPH; ++s) {
        const float4 top = lerp4(t00[s], t01[s], xf[s]);
        const float4 bot = lerp4(t10[s], t11[s], xf[s]);
        const float4 res = lerp4(top, bot, yf[s]);
        x[4 * s + 0] = res.x * fmask[s];
        x[4 * s + 1] = res.y * fmask[s];
        x[4 * s + 2] = res.z * fmask[s];
        x[4 * s + 3] = res.w * fmask[s];
    }

    // ---- layer in: (16) @ (16,32) + LN + relu ----
    float pre[HID], h[HID];
    #pragma unroll
    for (int j = 0; j < HID; ++j) pre[j] = b_in[j];
    #pragma unroll
    for (int k = 0; k < DIN; ++k) {
        const float xv = x[k];
        #pragma unroll
        for (int j = 0; j < HID; ++j)
            pre[j] = fmaf(xv, w_in[k * HID + j], pre[j]);
    }
    ln_relu(pre, g_in, bt_in, h);

    // ---- hidden layer 0 ----
    mm32(h, w_hid, b_hid, pre);
    ln_relu(pre, g_hid, bt_hid, h);

    // ---- hidden layer 1 ----
    mm32(h, w_hid + HID * HID, b_hid + HID, pre);
    ln_relu(pre, g_hid + HID, bt_hid + HID, h);

    // ---- output layer: (32) @ (32,3) ----
    float o0 = b_out[0], o1 = b_out[1], o2 = b_out[2];
    #pragma unroll
    for (int k = 0; k < HID; ++k) {
        const float hv = h[k];
        o0 = fmaf(hv, w_out[k * NOUT + 0], o0);
        o1 = fmaf(hv, w_out[k * NOUT + 1], o1);
        o2 = fmaf(hv, w_out[k * NOUT + 2], o2);
    }
    out[(size_t)ray * NOUT + 0] = o0;
    out[(size_t)ray * NOUT + 1] = o1;
    out[(size_t)ray * NOUT + 2] = o2;
}

extern "C" void kernel_launch(void* const* d_in, const int* in_sizes, int n_in,
                              void* d_out, int out_size, void* d_ws, size_t ws_size,
                              hipStream_t stream) {
    const float* inputs = (const float*)d_in[0];
    const float* tex    = (const float*)d_in[1];
    const float* w_in   = (const float*)d_in[2];
    const float* b_in   = (const float*)d_in[3];
    const float* g_in   = (const float*)d_in[4];
    const float* bt_in  = (const float*)d_in[5];
    const float* w_hid  = (const float*)d_in[6];
    const float* b_hid  = (const float*)d_in[7];
    const float* g_hid  = (const float*)d_in[8];
    const float* bt_hid = (const float*)d_in[9];
    const float* w_out  = (const float*)d_in[10];
    const float* b_out  = (const float*)d_in[11];
    float* out = (float*)d_out;

    ray_mlp_kernel<<<NRAYS / 256, 256, 0, stream>>>(
        inputs, tex, w_in, b_in, g_in, bt_in,
        w_hid, b_hid, g_hid, bt_hid, w_out, b_out, out);
}